// Round 1
// baseline (45546.661 us; speedup 1.0000x reference)
//
#include <hip/hip_runtime.h>

#define NN 64

__device__ __forceinline__ double guard_d(double p) {
  if (fabs(p) < 1e-280) return (p >= 0.0) ? 1e-280 : -1e-280;
  return p;
}

// One workgroup (64 threads = 1 wave) per 64x64 matrix.
// LDS budget: T (double, 32KB) + Qm (float, 16KB) + F (float, 16KB) = 65536 B exactly.
__global__ __launch_bounds__(64) void spd64_kernel(const float* __restrict__ x,
                                                   float* __restrict__ out) {
  __shared__ double T[NN][NN];
  __shared__ float Qm[NN][NN];
  __shared__ float F[NN][NN];

  const int lane = threadIdx.x;
  const size_t mat = blockIdx.x;
  const float* src = x + mat * NN * NN;
  float* dst = out + mat * NN * NN;

  for (int r = 0; r < NN; ++r) {
    T[r][lane] = (double)src[r * NN + lane];
    Qm[r][lane] = (r == lane) ? 1.0f : 0.0f;
  }
  __syncthreads();

  // ---------------- Hessenberg reduction (double) ----------------
  double* vbuf = reinterpret_cast<double*>(&F[0][0]);  // scratch: 64 doubles (F unused yet)
  for (int k = 0; k <= NN - 3; ++k) {
    const int m = NN - 1 - k;  // length of column below diagonal
    double xt = (lane < m) ? T[k + 1 + lane][k] : 0.0;
    double ss = xt * xt;
    #pragma unroll
    for (int off = 32; off; off >>= 1) ss += __shfl_xor(ss, off);
    double x0 = T[k + 1][k];
    if (ss > 1e-280) {  // uniform across wave
      double sg = sqrt(ss);
      double beta = (x0 >= 0.0) ? -sg : sg;
      double tau = 1.0 / (ss - beta * x0);
      vbuf[lane] = (lane < m) ? (xt - ((lane == 0) ? beta : 0.0)) : 0.0;
      __syncthreads();
      {  // left apply P on rows k+1..N-1 ; lane = column
        const int j = lane;
        double acc = 0.0;
        for (int t = 0; t < m; ++t) acc += vbuf[t] * T[k + 1 + t][j];
        acc *= tau;
        for (int t = 0; t < m; ++t) T[k + 1 + t][j] -= vbuf[t] * acc;
      }
      __syncthreads();
      if (lane == 0) {  // exact zeros below subdiagonal (col k) — no conflict w/ right apply
        T[k + 1][k] = beta;
        for (int t = 1; t < m; ++t) T[k + 1 + t][k] = 0.0;
      }
      {  // right apply on T cols k+1.., and Q ; lane = row
        const int r = lane;
        double acc = 0.0;
        for (int t = 0; t < m; ++t) acc += T[r][k + 1 + t] * vbuf[t];
        acc *= tau;
        for (int t = 0; t < m; ++t) T[r][k + 1 + t] -= acc * vbuf[t];
        double qa = 0.0;
        for (int t = 0; t < m; ++t) qa += (double)Qm[r][k + 1 + t] * vbuf[t];
        qa *= tau;
        for (int t = 0; t < m; ++t)
          Qm[r][k + 1 + t] = (float)((double)Qm[r][k + 1 + t] - qa * vbuf[t]);
      }
      __syncthreads();
    }
  }

  // ---------------- Francis double-shift QR -> real Schur ----------------
  int hi = NN - 1;
  int its = 0, total = 0;
  while (hi > 0) {
    // deflation scan (all lanes read same LDS -> uniform)
    int lo = hi;
    bool brk = false;
    while (lo > 0) {
      double s = fabs(T[lo - 1][lo - 1]) + fabs(T[lo][lo]);
      if (s == 0.0) s = 1e-300;
      if (fabs(T[lo][lo - 1]) <= 1e-14 * s) { brk = true; break; }
      --lo;
    }
    if (brk) {
      __syncthreads();
      if (lane == 0) T[lo][lo - 1] = 0.0;
      __syncthreads();
    }
    if (lo == hi) { hi -= 1; its = 0; continue; }
    if (lo == hi - 1) {  // 2x2 window
      double a = T[hi - 1][hi - 1], b = T[hi - 1][hi];
      double c = T[hi][hi - 1], d = T[hi][hi];
      double pp = 0.5 * (a - d);
      double disc = pp * pp + b * c;
      if (disc >= 0.0) {  // real pair: rotate to triangular
        double sq = sqrt(disc);
        double mid = 0.5 * (a + d);
        double lam = mid + ((mid >= 0.0) ? sq : -sq);
        double u0 = b, u1 = lam - a;
        double w0 = lam - d, w1 = c;
        double nu = u0 * u0 + u1 * u1, nw = w0 * w0 + w1 * w1;
        double cs, sn;
        if (nu >= nw && nu > 1e-280) { double n2 = sqrt(nu); cs = u0 / n2; sn = u1 / n2; }
        else if (nw > 1e-280) { double n2 = sqrt(nw); cs = w0 / n2; sn = w1 / n2; }
        else { cs = 1.0; sn = 0.0; }
        {
          const int j = lane;
          double r0 = T[hi - 1][j], r1 = T[hi][j];
          T[hi - 1][j] = cs * r0 + sn * r1;
          T[hi][j] = cs * r1 - sn * r0;
        }
        __syncthreads();
        {
          const int r = lane;
          double c0 = T[r][hi - 1], c1 = T[r][hi];
          T[r][hi - 1] = cs * c0 + sn * c1;
          T[r][hi] = cs * c1 - sn * c0;
          double q0 = Qm[r][hi - 1], q1 = Qm[r][hi];
          Qm[r][hi - 1] = (float)(cs * q0 + sn * q1);
          Qm[r][hi] = (float)(cs * q1 - sn * q0);
        }
        __syncthreads();
        if (lane == 0) T[hi][hi - 1] = 0.0;
        __syncthreads();
      }
      // complex pair: keep 2x2 block as-is
      hi -= 2; its = 0; continue;
    }
    ++its; ++total;
    if (its > 40 || total > 2000) {  // safety: force deflation, guarantees termination
      __syncthreads();
      if (lane == 0) T[hi][hi - 1] = 0.0;
      __syncthreads();
      hi -= 1; its = 0; continue;
    }
    double sa, sb, sc2, sd2;
    if (its == 10 || its == 20 || its == 30) {  // exceptional shift (dlahqr style)
      double sx = fabs(T[hi][hi - 1]) + fabs(T[hi - 1][hi - 2]);
      sa = 0.75 * sx + T[hi][hi]; sb = -0.4375 * sx; sc2 = sx; sd2 = sa;
    } else {
      sa = T[hi - 1][hi - 1]; sb = T[hi - 1][hi];
      sc2 = T[hi][hi - 1]; sd2 = T[hi][hi];
    }
    double tr = sa + sd2;
    double det = sa * sd2 - sb * sc2;
    double h11 = T[lo][lo], h12 = T[lo][lo + 1], h21 = T[lo + 1][lo];
    double h22 = T[lo + 1][lo + 1], h32 = T[lo + 2][lo + 1];
    double bx = h11 * h11 + h12 * h21 - tr * h11 + det;
    double by = h21 * (h11 + h22 - tr);
    double bz = h21 * h32;
    for (int k = lo; k <= hi - 1; ++k) {  // bulge chase
      double vx, vy, vz;
      if (k > lo) {
        vx = T[k][k - 1]; vy = T[k + 1][k - 1];
        vz = (k + 2 <= hi) ? T[k + 2][k - 1] : 0.0;
      } else { vx = bx; vy = by; vz = bz; }
      const int nr = (k + 2 <= hi) ? 3 : 2;
      if (nr == 2) vz = 0.0;
      double ss2 = vx * vx + vy * vy + vz * vz;
      if (ss2 < 1e-280) continue;  // uniform
      double sg = sqrt(ss2);
      double beta = (vx >= 0.0) ? -sg : sg;
      double v0 = vx - beta, v1 = vy, v2 = vz;
      double tau = 1.0 / (ss2 - beta * vx);
      {  // left apply ; lane = column
        const int j = lane;
        double t0 = T[k][j], t1 = T[k + 1][j];
        double t2v = (nr == 3) ? T[k + 2][j] : 0.0;
        double tt = tau * (v0 * t0 + v1 * t1 + v2 * t2v);
        T[k][j] = t0 - v0 * tt;
        T[k + 1][j] = t1 - v1 * tt;
        if (nr == 3) T[k + 2][j] = t2v - v2 * tt;
      }
      __syncthreads();
      if (lane == 0 && k > lo) {  // exact bulge zeros (col k-1: disjoint from right apply)
        T[k][k - 1] = beta;
        T[k + 1][k - 1] = 0.0;
        if (nr == 3) T[k + 2][k - 1] = 0.0;
      }
      {  // right apply on T and Q ; lane = row
        const int r = lane;
        double c0 = T[r][k], c1 = T[r][k + 1];
        double c2v = (nr == 3) ? T[r][k + 2] : 0.0;
        double tt = tau * (c0 * v0 + c1 * v1 + c2v * v2);
        T[r][k] = c0 - tt * v0;
        T[r][k + 1] = c1 - tt * v1;
        if (nr == 3) T[r][k + 2] = c2v - tt * v2;
        double q0 = Qm[r][k], q1 = Qm[r][k + 1];
        double q2 = (nr == 3) ? (double)Qm[r][k + 2] : 0.0;
        double tq = tau * (q0 * v0 + q1 * v1 + q2 * v2);
        Qm[r][k] = (float)(q0 - tq * v0);
        Qm[r][k + 1] = (float)(q1 - tq * v1);
        if (nr == 3) Qm[r][k + 2] = (float)(q2 - tq * v2);
      }
      __syncthreads();
    }
  }
  __syncthreads();

  // ---------------- Parlett recurrence: F = f(T), f = |.| on spectrum ----------------
  unsigned long long pair_mask = __ballot((lane < NN - 1) && (T[lane + 1][lane] != 0.0));
  unsigned long long start_mask = ~(pair_mask << 1);  // bit p set iff block starts at p

  for (int r = 0; r < NN; ++r) F[r][lane] = 0.0f;
  __syncthreads();

  double mymod = 1e300;
  const bool isstart = (start_mask >> lane) & 1ULL;
  const bool ispair = (pair_mask >> lane) & 1ULL;
  if (isstart) {
    if (ispair) {  // complex pair: |lambda|^2 = det
      double a = T[lane][lane], b = T[lane][lane + 1];
      double c = T[lane + 1][lane], d = T[lane + 1][lane + 1];
      double rr = sqrt(fmax(a * d - b * c, 0.0));
      F[lane][lane] = (float)rr;
      F[lane + 1][lane + 1] = (float)rr;
      mymod = rr;
    } else {
      double a = fabs(T[lane][lane]);
      F[lane][lane] = (float)a;
      mymod = a;
    }
  }
  #pragma unroll
  for (int off = 32; off; off >>= 1) mymod = fmin(mymod, __shfl_xor(mymod, off));
  const double cshift = 1e-6 * mymod;
  __syncthreads();

  // process off-diagonal blocks in increasing start-distance; lane = si
  for (int dist = 1; dist < NN; ++dist) {
    const int si = lane, sj = lane + dist;
    bool active = (sj < NN) && ((start_mask >> si) & 1ULL) && ((start_mask >> sj) & 1ULL);
    if (active) {
      const int p = ((pair_mask >> si) & 1ULL) ? 2 : 1;
      const int q = ((pair_mask >> sj) & 1ULL) ? 2 : 1;
      double c00 = 0, c01 = 0, c10 = 0, c11 = 0;
      // C = sum_{k=si}^{<sj} F(si,k) T(k,sj)  -  sum_{k=si+p}^{<=sj} T(si,k) F(k,sj)
      int k = si;
      while (k < sj) {
        const bool kp = (pair_mask >> k) & 1ULL;
        double f00 = F[si][k];
        double f01 = kp ? (double)F[si][k + 1] : 0.0;
        double f10 = (p == 2) ? (double)F[si + 1][k] : 0.0;
        double f11 = (p == 2 && kp) ? (double)F[si + 1][k + 1] : 0.0;
        double t00 = T[k][sj];
        double t01 = (q == 2) ? T[k][sj + 1] : 0.0;
        double t10 = kp ? T[k + 1][sj] : 0.0;
        double t11 = (kp && q == 2) ? T[k + 1][sj + 1] : 0.0;
        c00 += f00 * t00 + f01 * t10;
        c01 += f00 * t01 + f01 * t11;
        c10 += f10 * t00 + f11 * t10;
        c11 += f10 * t01 + f11 * t11;
        k += kp ? 2 : 1;
      }
      k = si + p;
      while (k <= sj) {
        const bool kp = (pair_mask >> k) & 1ULL;
        double t00 = T[si][k];
        double t01 = kp ? T[si][k + 1] : 0.0;
        double t10 = (p == 2) ? T[si + 1][k] : 0.0;
        double t11 = (p == 2 && kp) ? T[si + 1][k + 1] : 0.0;
        double f00 = F[k][sj];
        double f01 = (q == 2) ? (double)F[k][sj + 1] : 0.0;
        double f10 = kp ? (double)F[k + 1][sj] : 0.0;
        double f11 = (kp && q == 2) ? (double)F[k + 1][sj + 1] : 0.0;
        c00 -= t00 * f00 + t01 * f10;
        c01 -= t00 * f01 + t01 * f11;
        c10 -= t10 * f00 + t11 * f10;
        c11 -= t10 * f01 + t11 * f11;
        k += kp ? 2 : 1;
      }
      // solve T_ii X - X T_jj = C
      double x00 = 0, x01 = 0, x10 = 0, x11 = 0;
      if (p == 1 && q == 1) {
        x00 = c00 / guard_d(T[si][si] - T[sj][sj]);
      } else if (p == 2 && q == 1) {
        double t = T[sj][sj];
        double m00 = T[si][si] - t, m01 = T[si][si + 1];
        double m10 = T[si + 1][si], m11 = T[si + 1][si + 1] - t;
        double dd = guard_d(m00 * m11 - m01 * m10);
        x00 = (m11 * c00 - m01 * c10) / dd;
        x10 = (m00 * c10 - m10 * c00) / dd;
      } else if (p == 1 && q == 2) {
        double t = T[si][si];
        double m00 = t - T[sj][sj], m01 = -T[sj][sj + 1];
        double m10 = -T[sj + 1][sj], m11 = t - T[sj + 1][sj + 1];
        double dd = guard_d(m00 * m11 - m01 * m10);
        x00 = (c00 * m11 - c01 * m10) / dd;
        x01 = (c01 * m00 - c00 * m01) / dd;
      } else {
        double A00 = T[si][si], A01 = T[si][si + 1];
        double A10 = T[si + 1][si], A11 = T[si + 1][si + 1];
        double B00 = T[sj][sj], B01 = T[sj][sj + 1];
        double B10 = T[sj + 1][sj], B11 = T[sj + 1][sj + 1];
        double M[4][5] = {
            {A00 - B00, A01, -B10, 0.0, c00},
            {A10, A11 - B00, 0.0, -B10, c10},
            {-B01, 0.0, A00 - B11, A01, c01},
            {0.0, -B01, A10, A11 - B11, c11}};
        #pragma unroll
        for (int cc = 0; cc < 4; ++cc) {
          #pragma unroll
          for (int rr2 = cc + 1; rr2 < 4; ++rr2) {  // bubble-max partial pivot (const idx)
            bool sw = fabs(M[rr2][cc]) > fabs(M[cc][cc]);
            #pragma unroll
            for (int t2 = cc; t2 < 5; ++t2) {
              double aa = M[cc][t2], bb = M[rr2][t2];
              M[cc][t2] = sw ? bb : aa;
              M[rr2][t2] = sw ? aa : bb;
            }
          }
          double inv = 1.0 / guard_d(M[cc][cc]);
          #pragma unroll
          for (int rr2 = cc + 1; rr2 < 4; ++rr2) {
            double f2 = M[rr2][cc] * inv;
            #pragma unroll
            for (int t2 = cc; t2 < 5; ++t2) M[rr2][t2] -= f2 * M[cc][t2];
          }
        }
        double z3 = M[3][4] / guard_d(M[3][3]);
        double z2 = (M[2][4] - M[2][3] * z3) / guard_d(M[2][2]);
        double z1 = (M[1][4] - M[1][3] * z3 - M[1][2] * z2) / guard_d(M[1][1]);
        double z0 = (M[0][4] - M[0][3] * z3 - M[0][2] * z2 - M[0][1] * z1) / guard_d(M[0][0]);
        x00 = z0; x10 = z1; x01 = z2; x11 = z3;
      }
      F[si][sj] = (float)x00;
      if (q == 2) F[si][sj + 1] = (float)x01;
      if (p == 2) {
        F[si + 1][sj] = (float)x10;
        if (q == 2) F[si + 1][sj + 1] = (float)x11;
      }
    }
    __syncthreads();
  }

  // ---------------- symmetrize + eps shift + out = Q Fs Q^T ----------------
  {
    const int r = lane;
    for (int j = r + 1; j < NN; ++j) {
      float v = 0.5f * (F[r][j] + F[j][r]);
      F[r][j] = v;
      F[j][r] = v;
    }
    F[r][r] += (float)cshift;
  }
  __syncthreads();

  float* W = reinterpret_cast<float*>(&T[0][0]);  // T dead; reuse as float W (16KB used)
  float acc[NN];
  #pragma unroll
  for (int i = 0; i < NN; ++i) acc[i] = 0.0f;
  for (int k = 0; k < NN; ++k) {  // W = Q * Fs ; lane = column
    float f = F[k][lane];
    #pragma unroll
    for (int i = 0; i < NN; ++i) acc[i] += Qm[i][k] * f;
  }
  #pragma unroll
  for (int i = 0; i < NN; ++i) W[i * NN + lane] = acc[i];
  __syncthreads();

  #pragma unroll
  for (int i = 0; i < NN; ++i) acc[i] = 0.0f;
  for (int k = 0; k < NN; ++k) {  // M = W * Q^T ; lane = column j
    float qv = Qm[lane][k];
    #pragma unroll
    for (int i = 0; i < NN; ++i) acc[i] += W[i * NN + k] * qv;
  }
  #pragma unroll
  for (int i = 0; i < NN; ++i) dst[i * NN + lane] = acc[i];
}

extern "C" void kernel_launch(void* const* d_in, const int* in_sizes, int n_in,
                              void* d_out, int out_size, void* d_ws, size_t ws_size,
                              hipStream_t stream) {
  const float* x = (const float*)d_in[0];
  float* out = (float*)d_out;
  const int nmat = in_sizes[0] / (NN * NN);  // 4096
  spd64_kernel<<<nmat, 64, 0, stream>>>(x, out);
}

// Round 2
// 20962.848 us; speedup vs baseline: 2.1727x; 2.1727x over previous
//
#include <hip/hip_runtime.h>

#define NN 64
#define LDP (NN + 1)  // +1 padding: kills the 32/64-way column-access bank conflicts

__device__ __forceinline__ double guard_d(double p) {
  if (fabs(p) < 1e-280) return (p >= 0.0) ? 1e-280 : -1e-280;
  return p;
}

// One workgroup (64 threads = 1 wave) per 64x64 matrix.
// LDS: Td (double, padded, 33280 B) + Qm (float, padded, 16640 B) + vbuf (512 B)
//    = 50432 B -> 3 blocks/CU (vs 2 at 64 KiB before).
// After Schur, Td's 33280 B region is split in place into Tf (float, 16640 B)
// and F (float, 16640 B) for the Parlett recurrence.
__global__ __launch_bounds__(64) void spd64_kernel(const float* __restrict__ x,
                                                   float* __restrict__ out) {
  __shared__ double Td[NN][LDP];
  __shared__ float Qm[NN][LDP];
  __shared__ double vbuf[NN];

  const int lane = threadIdx.x;
  const size_t mat = blockIdx.x;
  const float* src = x + mat * NN * NN;
  float* dst = out + mat * NN * NN;

  for (int r = 0; r < NN; ++r) {
    Td[r][lane] = (double)src[r * NN + lane];
    Qm[r][lane] = (r == lane) ? 1.0f : 0.0f;
  }
  __syncthreads();

  // ---------------- Hessenberg reduction (double) ----------------
  for (int k = 0; k <= NN - 3; ++k) {
    const int m = NN - 1 - k;  // length of column below diagonal
    double xt = (lane < m) ? Td[k + 1 + lane][k] : 0.0;
    double ss = xt * xt;
    #pragma unroll
    for (int off = 32; off; off >>= 1) ss += __shfl_xor(ss, off);
    double x0 = Td[k + 1][k];
    if (ss > 1e-280) {  // uniform across wave
      double sg = sqrt(ss);
      double beta = (x0 >= 0.0) ? -sg : sg;
      double tau = 1.0 / (ss - beta * x0);
      vbuf[lane] = (lane < m) ? (xt - ((lane == 0) ? beta : 0.0)) : 0.0;
      __syncthreads();
      // left apply P on rows k+1..N-1; lane = column. Cols < k are exact zeros
      // in these rows (prior reflectors), col k overwritten exactly below.
      if (lane >= k + 1) {
        const int j = lane;
        double acc = 0.0;
        for (int t = 0; t < m; ++t) acc += vbuf[t] * Td[k + 1 + t][j];
        acc *= tau;
        for (int t = 0; t < m; ++t) Td[k + 1 + t][j] -= vbuf[t] * acc;
      }
      __syncthreads();
      if (lane == 0) {  // exact zeros below subdiagonal (col k) — disjoint from right apply
        Td[k + 1][k] = beta;
        for (int t = 1; t < m; ++t) Td[k + 1 + t][k] = 0.0;
      }
      {  // right apply on T cols k+1.., and Q; lane = row
        const int r = lane;
        double acc = 0.0;
        for (int t = 0; t < m; ++t) acc += Td[r][k + 1 + t] * vbuf[t];
        acc *= tau;
        for (int t = 0; t < m; ++t) Td[r][k + 1 + t] -= acc * vbuf[t];
        double qa = 0.0;
        for (int t = 0; t < m; ++t) qa += (double)Qm[r][k + 1 + t] * vbuf[t];
        qa *= tau;
        for (int t = 0; t < m; ++t)
          Qm[r][k + 1 + t] = (float)((double)Qm[r][k + 1 + t] - qa * vbuf[t]);
      }
      __syncthreads();
    }
  }

  // ---------------- Francis double-shift QR -> real Schur ----------------
  int hi = NN - 1;
  int its = 0, total = 0;
  while (hi > 0) {
    // parallel deflation scan: lane l tests subdiag (l-1,l); pick largest small index <= hi
    bool small = false;
    if (lane >= 1 && lane <= hi) {
      double s = fabs(Td[lane - 1][lane - 1]) + fabs(Td[lane][lane]);
      if (s == 0.0) s = 1e-300;
      small = fabs(Td[lane][lane - 1]) <= 1e-14 * s;
    }
    unsigned long long msk = __ballot(small) | 1ULL;
    if (hi < 63) msk &= (2ULL << hi) - 1ULL;
    const int lo = 63 - __clzll(msk);
    if (lo > 0) {
      __syncthreads();
      if (lane == 0) Td[lo][lo - 1] = 0.0;
      __syncthreads();
    }
    if (lo == hi) { hi -= 1; its = 0; continue; }
    if (lo == hi - 1) {  // 2x2 window
      double a = Td[hi - 1][hi - 1], b = Td[hi - 1][hi];
      double c = Td[hi][hi - 1], d = Td[hi][hi];
      double pp = 0.5 * (a - d);
      double disc = pp * pp + b * c;
      if (disc >= 0.0) {  // real pair: rotate to triangular
        double sq = sqrt(disc);
        double mid = 0.5 * (a + d);
        double lam = mid + ((mid >= 0.0) ? sq : -sq);
        double u0 = b, u1 = lam - a;
        double w0 = lam - d, w1 = c;
        double nu = u0 * u0 + u1 * u1, nw = w0 * w0 + w1 * w1;
        double cs, sn;
        if (nu >= nw && nu > 1e-280) { double n2 = sqrt(nu); cs = u0 / n2; sn = u1 / n2; }
        else if (nw > 1e-280) { double n2 = sqrt(nw); cs = w0 / n2; sn = w1 / n2; }
        else { cs = 1.0; sn = 0.0; }
        {
          const int j = lane;
          double r0 = Td[hi - 1][j], r1 = Td[hi][j];
          Td[hi - 1][j] = cs * r0 + sn * r1;
          Td[hi][j] = cs * r1 - sn * r0;
        }
        __syncthreads();
        {
          const int r = lane;
          double c0 = Td[r][hi - 1], c1 = Td[r][hi];
          Td[r][hi - 1] = cs * c0 + sn * c1;
          Td[r][hi] = cs * c1 - sn * c0;
          double q0 = Qm[r][hi - 1], q1 = Qm[r][hi];
          Qm[r][hi - 1] = (float)(cs * q0 + sn * q1);
          Qm[r][hi] = (float)(cs * q1 - sn * q0);
        }
        __syncthreads();
        if (lane == 0) Td[hi][hi - 1] = 0.0;
        __syncthreads();
      }
      hi -= 2; its = 0; continue;
    }
    ++its; ++total;
    if (its > 40 || total > 2000) {  // safety: force deflation
      __syncthreads();
      if (lane == 0) Td[hi][hi - 1] = 0.0;
      __syncthreads();
      hi -= 1; its = 0; continue;
    }
    double sa, sb, sc2, sd2;
    if (its == 10 || its == 20 || its == 30) {  // exceptional shift (dlahqr style)
      double sx = fabs(Td[hi][hi - 1]) + fabs(Td[hi - 1][hi - 2]);
      sa = 0.75 * sx + Td[hi][hi]; sb = -0.4375 * sx; sc2 = sx; sd2 = sa;
    } else {
      sa = Td[hi - 1][hi - 1]; sb = Td[hi - 1][hi];
      sc2 = Td[hi][hi - 1]; sd2 = Td[hi][hi];
    }
    double tr = sa + sd2;
    double det = sa * sd2 - sb * sc2;
    double h11 = Td[lo][lo], h12 = Td[lo][lo + 1], h21 = Td[lo + 1][lo];
    double h22 = Td[lo + 1][lo + 1], h32 = Td[lo + 2][lo + 1];
    double bx = h11 * h11 + h12 * h21 - tr * h11 + det;
    double by = h21 * (h11 + h22 - tr);
    double bz = h21 * h32;
    for (int k = lo; k <= hi - 1; ++k) {  // bulge chase
      double vx, vy, vz;
      if (k > lo) {
        vx = Td[k][k - 1]; vy = Td[k + 1][k - 1];
        vz = (k + 2 <= hi) ? Td[k + 2][k - 1] : 0.0;
      } else { vx = bx; vy = by; vz = bz; }
      const int nr = (k + 2 <= hi) ? 3 : 2;
      if (nr == 2) vz = 0.0;
      double ss2 = vx * vx + vy * vy + vz * vz;
      if (ss2 < 1e-280) continue;  // uniform
      double sg = sqrt(ss2);
      double beta = (vx >= 0.0) ? -sg : sg;
      double v0 = vx - beta, v1 = vy, v2 = vz;
      double tau = 1.0 / (ss2 - beta * vx);
      // left apply; lane = column. Cols < jlo are structurally zero in rows k..k+2
      // (col k-1 overwritten exactly below).
      const int jlo = (k > lo) ? k : lo;
      if (lane >= jlo) {
        const int j = lane;
        double t0 = Td[k][j], t1 = Td[k + 1][j];
        double t2v = (nr == 3) ? Td[k + 2][j] : 0.0;
        double tt = tau * (v0 * t0 + v1 * t1 + v2 * t2v);
        Td[k][j] = t0 - v0 * tt;
        Td[k + 1][j] = t1 - v1 * tt;
        if (nr == 3) Td[k + 2][j] = t2v - v2 * tt;
      }
      __syncthreads();
      if (lane == 0 && k > lo) {  // exact bulge zeros (col k-1: disjoint from right apply)
        Td[k][k - 1] = beta;
        Td[k + 1][k - 1] = 0.0;
        if (nr == 3) Td[k + 2][k - 1] = 0.0;
      }
      {  // right apply on T (rows <= k+3 only: below is structurally zero) and Q (dense)
        const int r = lane;
        const int rmax = (k + 3 <= hi) ? (k + 3) : hi;
        if (r <= rmax) {
          double c0 = Td[r][k], c1 = Td[r][k + 1];
          double c2v = (nr == 3) ? Td[r][k + 2] : 0.0;
          double tt = tau * (c0 * v0 + c1 * v1 + c2v * v2);
          Td[r][k] = c0 - tt * v0;
          Td[r][k + 1] = c1 - tt * v1;
          if (nr == 3) Td[r][k + 2] = c2v - tt * v2;
        }
        double q0 = Qm[r][k], q1 = Qm[r][k + 1];
        double q2 = (nr == 3) ? (double)Qm[r][k + 2] : 0.0;
        double tq = tau * (q0 * v0 + q1 * v1 + q2 * v2);
        Qm[r][k] = (float)(q0 - tq * v0);
        Qm[r][k + 1] = (float)(q1 - tq * v1);
        if (nr == 3) Qm[r][k + 2] = (float)(q2 - tq * v2);
      }
      __syncthreads();
    }
  }
  __syncthreads();

  // ---------------- block structure + diag f-values from double T ----------------
  unsigned long long pair_mask = __ballot((lane < NN - 1) && (Td[lane + 1][lane] != 0.0));
  unsigned long long start_mask = ~(pair_mask << 1);  // bit p set iff block starts at p
  const bool isstart = (start_mask >> lane) & 1ULL;
  const bool ispair = (pair_mask >> lane) & 1ULL;
  double fdiag = 0.0, mymod = 1e300;
  if (isstart) {
    if (ispair) {  // complex pair: |lambda| = sqrt(det)
      double a = Td[lane][lane], b = Td[lane][lane + 1];
      double c = Td[lane + 1][lane], d = Td[lane + 1][lane + 1];
      fdiag = sqrt(fmax(a * d - b * c, 0.0));
    } else {
      fdiag = fabs(Td[lane][lane]);
    }
    mymod = fdiag;
  }
  #pragma unroll
  for (int off = 32; off; off >>= 1) mymod = fmin(mymod, __shfl_xor(mymod, off));
  const double cshift = 1e-6 * mymod;
  __syncthreads();

  // ---------------- in-place convert Td -> Tf(float); free half holds F ----------------
  float* Tf = reinterpret_cast<float*>(&Td[0][0]);
  float* Fp = Tf + NN * LDP;
  #define TF(r, c) ((double)Tf[(r) * LDP + (c)])
  #define FF(r, c) Fp[(r) * LDP + (c)]
  for (int r = 0; r < NN; ++r) {
    double v = Td[r][lane];
    __syncthreads();  // all lanes read row r before any lane overwrites low bytes
    Tf[r * LDP + lane] = (float)v;
    __syncthreads();
  }
  for (int r = 0; r < NN; ++r) FF(r, lane) = 0.0f;
  __syncthreads();
  if (isstart) {
    FF(lane, lane) = (float)fdiag;
    if (ispair) FF(lane + 1, lane + 1) = (float)fdiag;
  }
  __syncthreads();

  // ---------------- Parlett recurrence: F = f(T), f = |.| on spectrum ----------------
  for (int dist = 1; dist < NN; ++dist) {
    const int si = lane, sj = lane + dist;
    bool active = (sj < NN) && ((start_mask >> si) & 1ULL) && ((start_mask >> sj) & 1ULL);
    if (active) {
      const int p = ((pair_mask >> si) & 1ULL) ? 2 : 1;
      const int q = ((pair_mask >> sj) & 1ULL) ? 2 : 1;
      double c00 = 0, c01 = 0, c10 = 0, c11 = 0;
      int k = si;
      while (k < sj) {
        const bool kp = (pair_mask >> k) & 1ULL;
        double f00 = FF(si, k);
        double f01 = kp ? (double)FF(si, k + 1) : 0.0;
        double f10 = (p == 2) ? (double)FF(si + 1, k) : 0.0;
        double f11 = (p == 2 && kp) ? (double)FF(si + 1, k + 1) : 0.0;
        double t00 = TF(k, sj);
        double t01 = (q == 2) ? TF(k, sj + 1) : 0.0;
        double t10 = kp ? TF(k + 1, sj) : 0.0;
        double t11 = (kp && q == 2) ? TF(k + 1, sj + 1) : 0.0;
        c00 += f00 * t00 + f01 * t10;
        c01 += f00 * t01 + f01 * t11;
        c10 += f10 * t00 + f11 * t10;
        c11 += f10 * t01 + f11 * t11;
        k += kp ? 2 : 1;
      }
      k = si + p;
      while (k <= sj) {
        const bool kp = (pair_mask >> k) & 1ULL;
        double t00 = TF(si, k);
        double t01 = kp ? TF(si, k + 1) : 0.0;
        double t10 = (p == 2) ? TF(si + 1, k) : 0.0;
        double t11 = (p == 2 && kp) ? TF(si + 1, k + 1) : 0.0;
        double f00 = FF(k, sj);
        double f01 = (q == 2) ? (double)FF(k, sj + 1) : 0.0;
        double f10 = kp ? (double)FF(k + 1, sj) : 0.0;
        double f11 = (kp && q == 2) ? (double)FF(k + 1, sj + 1) : 0.0;
        c00 -= t00 * f00 + t01 * f10;
        c01 -= t00 * f01 + t01 * f11;
        c10 -= t10 * f00 + t11 * f10;
        c11 -= t10 * f01 + t11 * f11;
        k += kp ? 2 : 1;
      }
      // solve T_ii X - X T_jj = C
      double x00 = 0, x01 = 0, x10 = 0, x11 = 0;
      if (p == 1 && q == 1) {
        x00 = c00 / guard_d(TF(si, si) - TF(sj, sj));
      } else if (p == 2 && q == 1) {
        double t = TF(sj, sj);
        double m00 = TF(si, si) - t, m01 = TF(si, si + 1);
        double m10 = TF(si + 1, si), m11 = TF(si + 1, si + 1) - t;
        double dd = guard_d(m00 * m11 - m01 * m10);
        x00 = (m11 * c00 - m01 * c10) / dd;
        x10 = (m00 * c10 - m10 * c00) / dd;
      } else if (p == 1 && q == 2) {
        double t = TF(si, si);
        double m00 = t - TF(sj, sj), m01 = -TF(sj, sj + 1);
        double m10 = -TF(sj + 1, sj), m11 = t - TF(sj + 1, sj + 1);
        double dd = guard_d(m00 * m11 - m01 * m10);
        x00 = (c00 * m11 - c01 * m10) / dd;
        x01 = (c01 * m00 - c00 * m01) / dd;
      } else {
        double A00 = TF(si, si), A01 = TF(si, si + 1);
        double A10 = TF(si + 1, si), A11 = TF(si + 1, si + 1);
        double B00 = TF(sj, sj), B01 = TF(sj, sj + 1);
        double B10 = TF(sj + 1, sj), B11 = TF(sj + 1, sj + 1);
        double M[4][5] = {
            {A00 - B00, A01, -B10, 0.0, c00},
            {A10, A11 - B00, 0.0, -B10, c10},
            {-B01, 0.0, A00 - B11, A01, c01},
            {0.0, -B01, A10, A11 - B11, c11}};
        #pragma unroll
        for (int cc = 0; cc < 4; ++cc) {
          #pragma unroll
          for (int rr2 = cc + 1; rr2 < 4; ++rr2) {  // bubble-max partial pivot
            bool sw = fabs(M[rr2][cc]) > fabs(M[cc][cc]);
            #pragma unroll
            for (int t2 = cc; t2 < 5; ++t2) {
              double aa = M[cc][t2], bb = M[rr2][t2];
              M[cc][t2] = sw ? bb : aa;
              M[rr2][t2] = sw ? aa : bb;
            }
          }
          double inv = 1.0 / guard_d(M[cc][cc]);
          #pragma unroll
          for (int rr2 = cc + 1; rr2 < 4; ++rr2) {
            double f2 = M[rr2][cc] * inv;
            #pragma unroll
            for (int t2 = cc; t2 < 5; ++t2) M[rr2][t2] -= f2 * M[cc][t2];
          }
        }
        double z3 = M[3][4] / guard_d(M[3][3]);
        double z2 = (M[2][4] - M[2][3] * z3) / guard_d(M[2][2]);
        double z1 = (M[1][4] - M[1][3] * z3 - M[1][2] * z2) / guard_d(M[1][1]);
        double z0 = (M[0][4] - M[0][3] * z3 - M[0][2] * z2 - M[0][1] * z1) / guard_d(M[0][0]);
        x00 = z0; x10 = z1; x01 = z2; x11 = z3;
      }
      FF(si, sj) = (float)x00;
      if (q == 2) FF(si, sj + 1) = (float)x01;
      if (p == 2) {
        FF(si + 1, sj) = (float)x10;
        if (q == 2) FF(si + 1, sj + 1) = (float)x11;
      }
    }
    __syncthreads();
  }

  // ---------------- symmetrize + eps shift + out = Q Fs Q^T ----------------
  {
    const int r = lane;
    for (int j = r + 1; j < NN; ++j) {
      float v = 0.5f * (FF(r, j) + FF(j, r));
      FF(r, j) = v;
      FF(j, r) = v;
    }
    FF(r, r) += (float)cshift;
  }
  __syncthreads();

  float* W = Tf;  // Tf dead after Parlett; 16640 B region reused
  float acc[NN];
  #pragma unroll
  for (int i = 0; i < NN; ++i) acc[i] = 0.0f;
  for (int k = 0; k < NN; ++k) {  // W = Q * Fs ; lane = column
    float f = FF(k, lane);
    #pragma unroll
    for (int i = 0; i < NN; ++i) acc[i] += Qm[i][k] * f;
  }
  #pragma unroll
  for (int i = 0; i < NN; ++i) W[i * LDP + lane] = acc[i];
  __syncthreads();

  #pragma unroll
  for (int i = 0; i < NN; ++i) acc[i] = 0.0f;
  for (int k = 0; k < NN; ++k) {  // M = W * Q^T ; lane = column j
    float qv = Qm[lane][k];
    #pragma unroll
    for (int i = 0; i < NN; ++i) acc[i] += W[i * LDP + k] * qv;
  }
  #pragma unroll
  for (int i = 0; i < NN; ++i) dst[i * NN + lane] = acc[i];
}

extern "C" void kernel_launch(void* const* d_in, const int* in_sizes, int n_in,
                              void* d_out, int out_size, void* d_ws, size_t ws_size,
                              hipStream_t stream) {
  const float* x = (const float*)d_in[0];
  float* out = (float*)d_out;
  const int nmat = in_sizes[0] / (NN * NN);  // 4096
  spd64_kernel<<<nmat, 64, 0, stream>>>(x, out);
}

// Round 3
// 20674.228 us; speedup vs baseline: 2.2031x; 1.0140x over previous
//
#include <hip/hip_runtime.h>

#define NN 64
#define LDP (NN + 1)  // +1 padding: kills the 32/64-way column-access bank conflicts

__device__ __forceinline__ double guard_d(double p) {
  if (fabs(p) < 1e-280) return (p >= 0.0) ? 1e-280 : -1e-280;
  return p;
}

// Wave-uniform lane read of a double via v_readlane (no LDS, no lgkmcnt).
__device__ __forceinline__ double readlane_d(double v, int l) {
  union { double d; int i[2]; } u;
  u.d = v;
  int a = __builtin_amdgcn_readlane(u.i[0], l);
  int b = __builtin_amdgcn_readlane(u.i[1], l);
  union { double d; int i[2]; } w;
  w.i[0] = a; w.i[1] = b;
  return w.d;
}

// One workgroup (64 threads = 1 wave) per 64x64 matrix.
// LDS: Td (double, padded, 33280 B) + Qm (float, padded, 16640 B) + vbuf (512 B)
//    = 50432 B -> 3 blocks/CU.
// Bulge chase: next bulge column handed off in registers via v_readlane, so the
// reflector's sqrt+div overlaps the LDS write drain instead of serializing
// behind an LDS read.
__global__ __launch_bounds__(64) void spd64_kernel(const float* __restrict__ x,
                                                   float* __restrict__ out) {
  __shared__ double Td[NN][LDP];
  __shared__ float Qm[NN][LDP];
  __shared__ double vbuf[NN];

  const int lane = threadIdx.x;
  const size_t mat = blockIdx.x;
  const float* src = x + mat * NN * NN;
  float* dst = out + mat * NN * NN;

  for (int r = 0; r < NN; ++r) {
    Td[r][lane] = (double)src[r * NN + lane];
    Qm[r][lane] = (r == lane) ? 1.0f : 0.0f;
  }
  __syncthreads();

  // ---------------- Hessenberg reduction (double) ----------------
  for (int k = 0; k <= NN - 3; ++k) {
    const int m = NN - 1 - k;
    double xt = (lane < m) ? Td[k + 1 + lane][k] : 0.0;
    double ss = xt * xt;
    #pragma unroll
    for (int off = 32; off; off >>= 1) ss += __shfl_xor(ss, off);
    double x0 = Td[k + 1][k];
    if (ss > 1e-280) {  // uniform across wave
      double sg = sqrt(ss);
      double beta = (x0 >= 0.0) ? -sg : sg;
      double tau = 1.0 / (ss - beta * x0);
      vbuf[lane] = (lane < m) ? (xt - ((lane == 0) ? beta : 0.0)) : 0.0;
      __syncthreads();
      if (lane >= k + 1) {  // left apply; cols < k structurally zero in rows k+1..
        const int j = lane;
        double acc = 0.0;
        for (int t = 0; t < m; ++t) acc += vbuf[t] * Td[k + 1 + t][j];
        acc *= tau;
        for (int t = 0; t < m; ++t) Td[k + 1 + t][j] -= vbuf[t] * acc;
      }
      __syncthreads();
      if (lane == 0) {  // exact zeros below subdiagonal (col k)
        Td[k + 1][k] = beta;
        for (int t = 1; t < m; ++t) Td[k + 1 + t][k] = 0.0;
      }
      {  // right apply on T cols k+1.., and Q; lane = row
        const int r = lane;
        double acc = 0.0;
        for (int t = 0; t < m; ++t) acc += Td[r][k + 1 + t] * vbuf[t];
        acc *= tau;
        for (int t = 0; t < m; ++t) Td[r][k + 1 + t] -= acc * vbuf[t];
        double qa = 0.0;
        for (int t = 0; t < m; ++t) qa += (double)Qm[r][k + 1 + t] * vbuf[t];
        qa *= tau;
        for (int t = 0; t < m; ++t)
          Qm[r][k + 1 + t] = (float)((double)Qm[r][k + 1 + t] - qa * vbuf[t]);
      }
      __syncthreads();
    }
  }

  // ---------------- Francis double-shift QR -> real Schur ----------------
  int hi = NN - 1;
  int its = 0, total = 0;
  while (hi > 0) {
    // parallel deflation scan
    bool small = false;
    if (lane >= 1 && lane <= hi) {
      double s = fabs(Td[lane - 1][lane - 1]) + fabs(Td[lane][lane]);
      if (s == 0.0) s = 1e-300;
      small = fabs(Td[lane][lane - 1]) <= 1e-12 * s;
    }
    unsigned long long msk = __ballot(small) | 1ULL;
    if (hi < 63) msk &= (2ULL << hi) - 1ULL;
    const int lo = 63 - __clzll(msk);
    if (lo > 0) {
      __syncthreads();
      if (lane == 0) Td[lo][lo - 1] = 0.0;
      __syncthreads();
    }
    if (lo == hi) { hi -= 1; its = 0; continue; }
    if (lo == hi - 1) {  // 2x2 window
      double a = Td[hi - 1][hi - 1], b = Td[hi - 1][hi];
      double c = Td[hi][hi - 1], d = Td[hi][hi];
      double pp = 0.5 * (a - d);
      double disc = pp * pp + b * c;
      if (disc >= 0.0) {  // real pair: rotate to triangular
        double sq = sqrt(disc);
        double mid = 0.5 * (a + d);
        double lam = mid + ((mid >= 0.0) ? sq : -sq);
        double u0 = b, u1 = lam - a;
        double w0 = lam - d, w1 = c;
        double nu = u0 * u0 + u1 * u1, nw = w0 * w0 + w1 * w1;
        double cs, sn;
        if (nu >= nw && nu > 1e-280) { double n2 = sqrt(nu); cs = u0 / n2; sn = u1 / n2; }
        else if (nw > 1e-280) { double n2 = sqrt(nw); cs = w0 / n2; sn = w1 / n2; }
        else { cs = 1.0; sn = 0.0; }
        {
          const int j = lane;
          double r0 = Td[hi - 1][j], r1 = Td[hi][j];
          Td[hi - 1][j] = cs * r0 + sn * r1;
          Td[hi][j] = cs * r1 - sn * r0;
        }
        __syncthreads();
        {
          const int r = lane;
          double c0 = Td[r][hi - 1], c1 = Td[r][hi];
          Td[r][hi - 1] = cs * c0 + sn * c1;
          Td[r][hi] = cs * c1 - sn * c0;
          double q0 = Qm[r][hi - 1], q1 = Qm[r][hi];
          Qm[r][hi - 1] = (float)(cs * q0 + sn * q1);
          Qm[r][hi] = (float)(cs * q1 - sn * q0);
        }
        __syncthreads();
        if (lane == 0) Td[hi][hi - 1] = 0.0;
        __syncthreads();
      }
      hi -= 2; its = 0; continue;
    }
    ++its; ++total;
    if (its > 40 || total > 2000) {  // safety: force deflation
      __syncthreads();
      if (lane == 0) Td[hi][hi - 1] = 0.0;
      __syncthreads();
      hi -= 1; its = 0; continue;
    }
    double sa, sb, sc2, sd2;
    if (its == 10 || its == 20 || its == 30) {  // exceptional shift (dlahqr style)
      double sx = fabs(Td[hi][hi - 1]) + fabs(Td[hi - 1][hi - 2]);
      sa = 0.75 * sx + Td[hi][hi]; sb = -0.4375 * sx; sc2 = sx; sd2 = sa;
    } else {
      sa = Td[hi - 1][hi - 1]; sb = Td[hi - 1][hi];
      sc2 = Td[hi][hi - 1]; sd2 = Td[hi][hi];
    }
    double tr = sa + sd2;
    double det = sa * sd2 - sb * sc2;
    double h11 = Td[lo][lo], h12 = Td[lo][lo + 1], h21 = Td[lo + 1][lo];
    double h22 = Td[lo + 1][lo + 1], h32 = Td[lo + 2][lo + 1];
    // bulge column carried in registers across k-steps (v_readlane handoff)
    double cvx = h11 * h11 + h12 * h21 - tr * h11 + det;
    double cvy = h21 * (h11 + h22 - tr);
    double cvz = h21 * h32;
    for (int k = lo; k <= hi - 1; ++k) {  // bulge chase
      const int nr = (k + 2 <= hi) ? 3 : 2;
      const double vx = cvx, vy = cvy, vz = (nr == 3) ? cvz : 0.0;
      double ss2 = vx * vx + vy * vy + vz * vz;
      if (ss2 < 1e-280) break;  // bulge collapsed; remaining applies are identity
      double sg = sqrt(ss2);
      double beta = (vx >= 0.0) ? -sg : sg;
      double v0 = vx - beta, v1 = vy, v2 = vz;
      double tau = 1.0 / (ss2 - beta * vx);
      const int r = lane;
      // hoist Q loads: producers synced a full phase ago -> latency hides under left apply
      double q0 = Qm[r][k], q1 = Qm[r][k + 1];
      double q2 = (nr == 3) ? (double)Qm[r][k + 2] : 0.0;
      // left apply; lane = column >= jlo (cols below are structurally zero in rows k..k+2)
      const int jlo = (k > lo) ? k : lo;
      if (lane >= jlo) {
        const int j = lane;
        double t0 = Td[k][j], t1 = Td[k + 1][j];
        double t2v = (nr == 3) ? Td[k + 2][j] : 0.0;
        double tt = tau * (v0 * t0 + v1 * t1 + v2 * t2v);
        Td[k][j] = t0 - v0 * tt;
        Td[k + 1][j] = t1 - v1 * tt;
        if (nr == 3) Td[k + 2][j] = t2v - v2 * tt;
      }
      __syncthreads();
      if (lane == 0 && k > lo) {  // exact bulge zeros (col k-1: disjoint from right apply)
        Td[k][k - 1] = beta;
        Td[k + 1][k - 1] = 0.0;
        if (nr == 3) Td[k + 2][k - 1] = 0.0;
      }
      // right apply on T (rows <= k+3) and Q (dense)
      const int rmax = (k + 3 <= hi) ? (k + 3) : hi;
      double n0 = 0.0, n1 = 0.0, n2 = 0.0;
      if (r <= rmax) {
        double c0 = Td[r][k], c1 = Td[r][k + 1];
        double c2v = (nr == 3) ? Td[r][k + 2] : 0.0;
        double tt = tau * (c0 * v0 + c1 * v1 + c2v * v2);
        n0 = c0 - tt * v0;
        n1 = c1 - tt * v1;
        n2 = c2v - tt * v2;
      }
      // register handoff of next bulge column BEFORE the LDS writes:
      // next step's (vx,vy,vz) = new T[k+1..k+3][k] = n0 in lanes k+1..k+3.
      {
        const int ly = (k + 2 <= 63) ? (k + 2) : 0;
        const int lz = (k + 3 <= hi) ? (k + 3) : 0;
        cvx = readlane_d(n0, k + 1);
        cvy = readlane_d(n0, ly);
        cvz = readlane_d(n0, lz);
      }
      if (r <= rmax) {
        Td[r][k] = n0;
        Td[r][k + 1] = n1;
        if (nr == 3) Td[r][k + 2] = n2;
      }
      {
        double tq = tau * (q0 * v0 + q1 * v1 + q2 * v2);
        Qm[r][k] = (float)(q0 - tq * v0);
        Qm[r][k + 1] = (float)(q1 - tq * v1);
        if (nr == 3) Qm[r][k + 2] = (float)(q2 - tq * v2);
      }
      __syncthreads();
    }
  }
  __syncthreads();

  // ---------------- block structure + diag f-values from double T ----------------
  unsigned long long pair_mask = __ballot((lane < NN - 1) && (Td[lane + 1][lane] != 0.0));
  unsigned long long start_mask = ~(pair_mask << 1);  // bit p set iff block starts at p
  const bool isstart = (start_mask >> lane) & 1ULL;
  const bool ispair = (pair_mask >> lane) & 1ULL;
  double fdiag = 0.0, mymod = 1e300;
  if (isstart) {
    if (ispair) {  // complex pair: |lambda| = sqrt(det)
      double a = Td[lane][lane], b = Td[lane][lane + 1];
      double c = Td[lane + 1][lane], d = Td[lane + 1][lane + 1];
      fdiag = sqrt(fmax(a * d - b * c, 0.0));
    } else {
      fdiag = fabs(Td[lane][lane]);
    }
    mymod = fdiag;
  }
  #pragma unroll
  for (int off = 32; off; off >>= 1) mymod = fmin(mymod, __shfl_xor(mymod, off));
  const double cshift = 1e-6 * mymod;
  __syncthreads();

  // ---------------- in-place convert Td -> Tf(float); free half holds F ----------------
  float* Tf = reinterpret_cast<float*>(&Td[0][0]);
  float* Fp = Tf + NN * LDP;
  #define TF(r, c) ((double)Tf[(r) * LDP + (c)])
  #define FF(r, c) Fp[(r) * LDP + (c)]
  for (int r = 0; r < NN; ++r) {
    double v = Td[r][lane];
    __syncthreads();  // all lanes read row r before any lane overwrites low bytes
    Tf[r * LDP + lane] = (float)v;
    __syncthreads();
  }
  for (int r = 0; r < NN; ++r) FF(r, lane) = 0.0f;
  __syncthreads();
  if (isstart) {
    FF(lane, lane) = (float)fdiag;
    if (ispair) FF(lane + 1, lane + 1) = (float)fdiag;
  }
  __syncthreads();

  // ---------------- Parlett recurrence: F = f(T), f = |.| on spectrum ----------------
  for (int dist = 1; dist < NN; ++dist) {
    const int si = lane, sj = lane + dist;
    bool active = (sj < NN) && ((start_mask >> si) & 1ULL) && ((start_mask >> sj) & 1ULL);
    if (active) {
      const int p = ((pair_mask >> si) & 1ULL) ? 2 : 1;
      const int q = ((pair_mask >> sj) & 1ULL) ? 2 : 1;
      double c00 = 0, c01 = 0, c10 = 0, c11 = 0;
      int k = si;
      while (k < sj) {
        const bool kp = (pair_mask >> k) & 1ULL;
        double f00 = FF(si, k);
        double f01 = kp ? (double)FF(si, k + 1) : 0.0;
        double f10 = (p == 2) ? (double)FF(si + 1, k) : 0.0;
        double f11 = (p == 2 && kp) ? (double)FF(si + 1, k + 1) : 0.0;
        double t00 = TF(k, sj);
        double t01 = (q == 2) ? TF(k, sj + 1) : 0.0;
        double t10 = kp ? TF(k + 1, sj) : 0.0;
        double t11 = (kp && q == 2) ? TF(k + 1, sj + 1) : 0.0;
        c00 += f00 * t00 + f01 * t10;
        c01 += f00 * t01 + f01 * t11;
        c10 += f10 * t00 + f11 * t10;
        c11 += f10 * t01 + f11 * t11;
        k += kp ? 2 : 1;
      }
      k = si + p;
      while (k <= sj) {
        const bool kp = (pair_mask >> k) & 1ULL;
        double t00 = TF(si, k);
        double t01 = kp ? TF(si, k + 1) : 0.0;
        double t10 = (p == 2) ? TF(si + 1, k) : 0.0;
        double t11 = (p == 2 && kp) ? TF(si + 1, k + 1) : 0.0;
        double f00 = FF(k, sj);
        double f01 = (q == 2) ? (double)FF(k, sj + 1) : 0.0;
        double f10 = kp ? (double)FF(k + 1, sj) : 0.0;
        double f11 = (kp && q == 2) ? (double)FF(k + 1, sj + 1) : 0.0;
        c00 -= t00 * f00 + t01 * f10;
        c01 -= t00 * f01 + t01 * f11;
        c10 -= t10 * f00 + t11 * f10;
        c11 -= t10 * f01 + t11 * f11;
        k += kp ? 2 : 1;
      }
      // solve T_ii X - X T_jj = C
      double x00 = 0, x01 = 0, x10 = 0, x11 = 0;
      if (p == 1 && q == 1) {
        x00 = c00 / guard_d(TF(si, si) - TF(sj, sj));
      } else if (p == 2 && q == 1) {
        double t = TF(sj, sj);
        double m00 = TF(si, si) - t, m01 = TF(si, si + 1);
        double m10 = TF(si + 1, si), m11 = TF(si + 1, si + 1) - t;
        double dd = guard_d(m00 * m11 - m01 * m10);
        x00 = (m11 * c00 - m01 * c10) / dd;
        x10 = (m00 * c10 - m10 * c00) / dd;
      } else if (p == 1 && q == 2) {
        double t = TF(si, si);
        double m00 = t - TF(sj, sj), m01 = -TF(sj, sj + 1);
        double m10 = -TF(sj + 1, sj), m11 = t - TF(sj + 1, sj + 1);
        double dd = guard_d(m00 * m11 - m01 * m10);
        x00 = (c00 * m11 - c01 * m10) / dd;
        x01 = (c01 * m00 - c00 * m01) / dd;
      } else {
        double A00 = TF(si, si), A01 = TF(si, si + 1);
        double A10 = TF(si + 1, si), A11 = TF(si + 1, si + 1);
        double B00 = TF(sj, sj), B01 = TF(sj, sj + 1);
        double B10 = TF(sj + 1, sj), B11 = TF(sj + 1, sj + 1);
        double M[4][5] = {
            {A00 - B00, A01, -B10, 0.0, c00},
            {A10, A11 - B00, 0.0, -B10, c10},
            {-B01, 0.0, A00 - B11, A01, c01},
            {0.0, -B01, A10, A11 - B11, c11}};
        #pragma unroll
        for (int cc = 0; cc < 4; ++cc) {
          #pragma unroll
          for (int rr2 = cc + 1; rr2 < 4; ++rr2) {  // bubble-max partial pivot
            bool sw = fabs(M[rr2][cc]) > fabs(M[cc][cc]);
            #pragma unroll
            for (int t2 = cc; t2 < 5; ++t2) {
              double aa = M[cc][t2], bb = M[rr2][t2];
              M[cc][t2] = sw ? bb : aa;
              M[rr2][t2] = sw ? aa : bb;
            }
          }
          double inv = 1.0 / guard_d(M[cc][cc]);
          #pragma unroll
          for (int rr2 = cc + 1; rr2 < 4; ++rr2) {
            double f2 = M[rr2][cc] * inv;
            #pragma unroll
            for (int t2 = cc; t2 < 5; ++t2) M[rr2][t2] -= f2 * M[cc][t2];
          }
        }
        double z3 = M[3][4] / guard_d(M[3][3]);
        double z2 = (M[2][4] - M[2][3] * z3) / guard_d(M[2][2]);
        double z1 = (M[1][4] - M[1][3] * z3 - M[1][2] * z2) / guard_d(M[1][1]);
        double z0 = (M[0][4] - M[0][3] * z3 - M[0][2] * z2 - M[0][1] * z1) / guard_d(M[0][0]);
        x00 = z0; x10 = z1; x01 = z2; x11 = z3;
      }
      FF(si, sj) = (float)x00;
      if (q == 2) FF(si, sj + 1) = (float)x01;
      if (p == 2) {
        FF(si + 1, sj) = (float)x10;
        if (q == 2) FF(si + 1, sj + 1) = (float)x11;
      }
    }
    __syncthreads();
  }

  // ---------------- symmetrize + eps shift + out = Q Fs Q^T ----------------
  {
    const int r = lane;
    for (int j = r + 1; j < NN; ++j) {
      float v = 0.5f * (FF(r, j) + FF(j, r));
      FF(r, j) = v;
      FF(j, r) = v;
    }
    FF(r, r) += (float)cshift;
  }
  __syncthreads();

  float* W = Tf;  // Tf dead after Parlett; region reused
  float acc[NN];
  #pragma unroll
  for (int i = 0; i < NN; ++i) acc[i] = 0.0f;
  for (int k = 0; k < NN; ++k) {  // W = Q * Fs ; lane = column
    float f = FF(k, lane);
    #pragma unroll
    for (int i = 0; i < NN; ++i) acc[i] += Qm[i][k] * f;
  }
  #pragma unroll
  for (int i = 0; i < NN; ++i) W[i * LDP + lane] = acc[i];
  __syncthreads();

  #pragma unroll
  for (int i = 0; i < NN; ++i) acc[i] = 0.0f;
  for (int k = 0; k < NN; ++k) {  // M = W * Q^T ; lane = column j
    float qv = Qm[lane][k];
    #pragma unroll
    for (int i = 0; i < NN; ++i) acc[i] += W[i * LDP + k] * qv;
  }
  #pragma unroll
  for (int i = 0; i < NN; ++i) dst[i * NN + lane] = acc[i];
}

extern "C" void kernel_launch(void* const* d_in, const int* in_sizes, int n_in,
                              void* d_out, int out_size, void* d_ws, size_t ws_size,
                              hipStream_t stream) {
  const float* x = (const float*)d_in[0];
  float* out = (float*)d_out;
  const int nmat = in_sizes[0] / (NN * NN);  // 4096
  spd64_kernel<<<nmat, 64, 0, stream>>>(x, out);
}

// Round 6
// 16128.389 us; speedup vs baseline: 2.8240x; 1.2819x over previous
//
#include <hip/hip_runtime.h>

#define NN 64
#define LDP (NN + 1)  // +1 padding: kills the 32/64-way column-access bank conflicts

__device__ __forceinline__ double guard_d(double p) {
  if (fabs(p) < 1e-280) return (p >= 0.0) ? 1e-280 : -1e-280;
  return p;
}

// Wave-uniform lane read of a double via v_readlane (no LDS, no lgkmcnt).
__device__ __forceinline__ double readlane_d(double v, int l) {
  union { double d; int i[2]; } u;
  u.d = v;
  int a = __builtin_amdgcn_readlane(u.i[0], l);
  int b = __builtin_amdgcn_readlane(u.i[1], l);
  union { double d; int i[2]; } w;
  w.i[0] = a; w.i[1] = b;
  return w.d;
}

// One workgroup (64 threads = 1 wave) per 64x64 matrix.
// R3-proven math (T all-double; Q: float STORAGE but DOUBLE arithmetic —
// float tau/v Householder math NaNs when a mid-sweep bulge collapses to
// sg<~1e-20: (float)tau=inf, (float)v=0, inf*0=NaN — the R4/R5 failure).
// One structural change vs R3: Q lives in this matrix's own d_out slot
// (transposed: Qg[c*64+r] = Q[r][c]; slot dead until the final store).
// LDS: Td double[64][65] (33280 B) + vbuf (512 B) = 33792 B -> 4 blocks/CU.
__global__ __launch_bounds__(64) void spd64_kernel(const float* __restrict__ x,
                                                   float* __restrict__ out) {
  __shared__ double Td[NN][LDP];
  __shared__ double vbuf[NN];

  const int lane = threadIdx.x;
  const size_t mat = blockIdx.x;
  const float* src = x + mat * NN * NN;
  float* dst = out + mat * NN * NN;
  float* Qg = dst;  // Q^T layout: Qg[c*64 + r] = Q[r][c]

  for (int r = 0; r < NN; ++r) Td[r][lane] = (double)src[r * NN + lane];
  for (int c = 0; c < NN; ++c) Qg[c * NN + lane] = (c == lane) ? 1.0f : 0.0f;
  __syncthreads();

  // ---------------- Hessenberg reduction (double T in LDS, float-storage Q in global) ----------------
  for (int k = 0; k <= NN - 3; ++k) {
    const int m = NN - 1 - k;
    double xt = (lane < m) ? Td[k + 1 + lane][k] : 0.0;
    double ss = xt * xt;
    #pragma unroll
    for (int off = 32; off; off >>= 1) ss += __shfl_xor(ss, off);
    double x0 = Td[k + 1][k];
    if (ss > 1e-280) {  // uniform across wave
      double sg = sqrt(ss);
      double beta = (x0 >= 0.0) ? -sg : sg;
      double tau = 1.0 / (ss - beta * x0);
      vbuf[lane] = (lane < m) ? (xt - ((lane == 0) ? beta : 0.0)) : 0.0;
      __syncthreads();
      if (lane >= k + 1) {  // left apply; cols < k structurally zero in rows k+1..
        const int j = lane;
        double acc = 0.0;
        for (int t = 0; t < m; ++t) acc += vbuf[t] * Td[k + 1 + t][j];
        acc *= tau;
        for (int t = 0; t < m; ++t) Td[k + 1 + t][j] -= vbuf[t] * acc;
      }
      __syncthreads();
      if (lane == 0) {  // exact zeros below subdiagonal (col k); disjoint from right apply
        Td[k + 1][k] = beta;
        for (int t = 1; t < m; ++t) Td[k + 1 + t][k] = 0.0;
      }
      {  // right apply on T cols k+1.. (LDS) and Q cols k+1.. (global, coalesced, DOUBLE math)
        const int r = lane;
        double acc = 0.0;
        double qa = 0.0;
        for (int t = 0; t < m; ++t) {
          double vt = vbuf[t];
          acc += Td[r][k + 1 + t] * vt;
          qa += (double)Qg[(k + 1 + t) * NN + r] * vt;
        }
        acc *= tau;
        qa *= tau;
        for (int t = 0; t < m; ++t) {
          double vt = vbuf[t];
          Td[r][k + 1 + t] -= acc * vt;
          Qg[(k + 1 + t) * NN + r] =
              (float)((double)Qg[(k + 1 + t) * NN + r] - qa * vt);
        }
      }
      __syncthreads();
    }
  }

  // ---------------- Francis double-shift QR -> real Schur ----------------
  int hi = NN - 1;
  int its = 0, total = 0;
  while (hi > 0) {
    bool small = false;
    if (lane >= 1 && lane <= hi) {
      double s = fabs(Td[lane - 1][lane - 1]) + fabs(Td[lane][lane]);
      if (s == 0.0) s = 1e-300;
      small = fabs(Td[lane][lane - 1]) <= 1e-12 * s;
    }
    unsigned long long msk = __ballot(small) | 1ULL;
    if (hi < 63) msk &= (2ULL << hi) - 1ULL;
    const int lo = 63 - __clzll(msk);
    if (lo > 0) {
      __syncthreads();
      if (lane == 0) Td[lo][lo - 1] = 0.0;
      __syncthreads();
    }
    if (lo == hi) { hi -= 1; its = 0; continue; }
    if (lo == hi - 1) {  // 2x2 window
      double a = Td[hi - 1][hi - 1], b = Td[hi - 1][hi];
      double c = Td[hi][hi - 1], d = Td[hi][hi];
      double pp = 0.5 * (a - d);
      double disc = pp * pp + b * c;
      if (disc >= 0.0) {  // real pair: rotate to triangular
        double sq = sqrt(disc);
        double mid = 0.5 * (a + d);
        double lam = mid + ((mid >= 0.0) ? sq : -sq);
        double u0 = b, u1 = lam - a;
        double w0 = lam - d, w1 = c;
        double nu = u0 * u0 + u1 * u1, nw = w0 * w0 + w1 * w1;
        double cs, sn;
        if (nu >= nw && nu > 1e-280) { double n2 = sqrt(nu); cs = u0 / n2; sn = u1 / n2; }
        else if (nw > 1e-280) { double n2 = sqrt(nw); cs = w0 / n2; sn = w1 / n2; }
        else { cs = 1.0; sn = 0.0; }
        {
          const int j = lane;
          double r0 = Td[hi - 1][j], r1 = Td[hi][j];
          Td[hi - 1][j] = cs * r0 + sn * r1;
          Td[hi][j] = cs * r1 - sn * r0;
        }
        __syncthreads();
        {
          const int r = lane;
          double c0 = Td[r][hi - 1], c1 = Td[r][hi];
          Td[r][hi - 1] = cs * c0 + sn * c1;
          Td[r][hi] = cs * c1 - sn * c0;
          double q0 = (double)Qg[(hi - 1) * NN + r], q1 = (double)Qg[hi * NN + r];
          Qg[(hi - 1) * NN + r] = (float)(cs * q0 + sn * q1);
          Qg[hi * NN + r] = (float)(cs * q1 - sn * q0);
        }
        __syncthreads();
        if (lane == 0) Td[hi][hi - 1] = 0.0;
        __syncthreads();
      }
      hi -= 2; its = 0; continue;
    }
    ++its; ++total;
    if (its > 40 || total > 2000) {  // safety: force deflation
      __syncthreads();
      if (lane == 0) Td[hi][hi - 1] = 0.0;
      __syncthreads();
      hi -= 1; its = 0; continue;
    }
    double sa, sb, sc2, sd2;
    if (its == 10 || its == 20 || its == 30) {  // exceptional shift (dlahqr style)
      double sx = fabs(Td[hi][hi - 1]) + fabs(Td[hi - 1][hi - 2]);
      sa = 0.75 * sx + Td[hi][hi]; sb = -0.4375 * sx; sc2 = sx; sd2 = sa;
    } else {
      sa = Td[hi - 1][hi - 1]; sb = Td[hi - 1][hi];
      sc2 = Td[hi][hi - 1]; sd2 = Td[hi][hi];
    }
    double tr = sa + sd2;
    double det = sa * sd2 - sb * sc2;
    double h11 = Td[lo][lo], h12 = Td[lo][lo + 1], h21 = Td[lo + 1][lo];
    double h22 = Td[lo + 1][lo + 1], h32 = Td[lo + 2][lo + 1];
    double cvx = h11 * h11 + h12 * h21 - tr * h11 + det;
    double cvy = h21 * (h11 + h22 - tr);
    double cvz = h21 * h32;
    // Q 3-column register window (cols k..k+2); DOUBLE registers, float storage
    double qw0 = (double)Qg[lo * NN + lane];
    double qw1 = (double)Qg[(lo + 1) * NN + lane];
    double qw2 = (double)Qg[(lo + 2) * NN + lane];
    bool broke = false;
    for (int k = lo; k <= hi - 1; ++k) {  // bulge chase
      const int nr = (k + 2 <= hi) ? 3 : 2;
      const double vx = cvx, vy = cvy, vz = (nr == 3) ? cvz : 0.0;
      double ss2 = vx * vx + vy * vy + vz * vz;
      if (ss2 < 1e-280) {  // bulge collapsed; flush pending window cols
        Qg[k * NN + lane] = (float)qw0;
        Qg[(k + 1) * NN + lane] = (float)qw1;
        if (k + 2 <= hi) Qg[(k + 2) * NN + lane] = (float)qw2;
        broke = true; break;
      }
      double sg = sqrt(ss2);
      double beta = (vx >= 0.0) ? -sg : sg;
      double v0 = vx - beta, v1 = vy, v2 = vz;
      double tau = 1.0 / (ss2 - beta * vx);
      double qnext = 0.0;
      if (k + 3 <= hi) qnext = (double)Qg[(k + 3) * NN + lane];  // prefetch next window col
      const int jlo = (k > lo) ? k : lo;
      if (lane >= jlo) {  // left apply
        const int j = lane;
        double t0 = Td[k][j], t1 = Td[k + 1][j];
        double t2v = (nr == 3) ? Td[k + 2][j] : 0.0;
        double tt = tau * (v0 * t0 + v1 * t1 + v2 * t2v);
        Td[k][j] = t0 - v0 * tt;
        Td[k + 1][j] = t1 - v1 * tt;
        if (nr == 3) Td[k + 2][j] = t2v - v2 * tt;
      }
      __syncthreads();
      if (lane == 0 && k > lo) {  // exact bulge zeros (col k-1)
        Td[k][k - 1] = beta;
        Td[k + 1][k - 1] = 0.0;
        if (nr == 3) Td[k + 2][k - 1] = 0.0;
      }
      const int rmax = (k + 3 <= hi) ? (k + 3) : hi;
      double n0 = 0.0, n1 = 0.0, n2 = 0.0;
      if (lane <= rmax) {  // right apply on T (rows below are structurally zero)
        double c0 = Td[lane][k], c1 = Td[lane][k + 1];
        double c2v = (nr == 3) ? Td[lane][k + 2] : 0.0;
        double tt = tau * (c0 * v0 + c1 * v1 + c2v * v2);
        n0 = c0 - tt * v0;
        n1 = c1 - tt * v1;
        n2 = c2v - tt * v2;
      }
      {  // register handoff of next bulge column before LDS writes
        const int ly = (k + 2 <= 63) ? (k + 2) : 0;
        const int lz = (k + 3 <= hi) ? (k + 3) : 0;
        cvx = readlane_d(n0, k + 1);
        cvy = readlane_d(n0, ly);
        cvz = readlane_d(n0, lz);
      }
      if (lane <= rmax) {
        Td[lane][k] = n0;
        Td[lane][k + 1] = n1;
        if (nr == 3) Td[lane][k + 2] = n2;
      }
      {  // Q window update — DOUBLE math (scale-safe for collapsed bulges)
        double tq = tau * (qw0 * v0 + qw1 * v1 + ((nr == 3) ? qw2 * v2 : 0.0));
        qw0 -= tq * v0;
        qw1 -= tq * v1;
        if (nr == 3) qw2 -= tq * v2;
      }
      Qg[k * NN + lane] = (float)qw0;  // col k final for this sweep
      qw0 = qw1; qw1 = qw2; qw2 = qnext;
      __syncthreads();
    }
    if (!broke) Qg[hi * NN + lane] = (float)qw0;  // flush last window col
  }
  __syncthreads();

  // ---------------- block structure + diag f-values from double T ----------------
  unsigned long long pair_mask = __ballot((lane < NN - 1) && (Td[lane + 1][lane] != 0.0));
  unsigned long long start_mask = ~(pair_mask << 1);  // bit p set iff block starts at p
  const bool isstart = (start_mask >> lane) & 1ULL;
  const bool ispair = (pair_mask >> lane) & 1ULL;
  double fdiag = 0.0, mymod = 1e300;
  if (isstart) {
    if (ispair) {  // complex pair: |lambda| = sqrt(det)
      double a = Td[lane][lane], b = Td[lane][lane + 1];
      double c = Td[lane + 1][lane], d = Td[lane + 1][lane + 1];
      fdiag = sqrt(fmax(a * d - b * c, 0.0));
    } else {
      fdiag = fabs(Td[lane][lane]);
    }
    mymod = fdiag;
  }
  #pragma unroll
  for (int off = 32; off; off >>= 1) mymod = fmin(mymod, __shfl_xor(mymod, off));
  const double cshift = 1e-6 * mymod;
  __syncthreads();

  // ---------------- in-place convert Td -> Tf(float); free half holds F ----------------
  float* Tf = reinterpret_cast<float*>(&Td[0][0]);
  float* Fp = Tf + NN * LDP;
  #define TF(r, c) ((double)Tf[(r) * LDP + (c)])
  #define FF(r, c) Fp[(r) * LDP + (c)]
  for (int r = 0; r < NN; ++r) {
    double v = Td[r][lane];
    __syncthreads();  // all lanes read double row r before any lane overwrites low bytes
    Tf[r * LDP + lane] = (float)v;
    __syncthreads();
  }
  for (int r = 0; r < NN; ++r) FF(r, lane) = 0.0f;
  __syncthreads();
  if (isstart) {
    FF(lane, lane) = (float)fdiag;
    if (ispair) FF(lane + 1, lane + 1) = (float)fdiag;
  }
  __syncthreads();

  // ---------------- Parlett recurrence: F = f(T), f = |.| on spectrum ----------------
  for (int dist = 1; dist < NN; ++dist) {
    const int si = lane, sj = lane + dist;
    bool active = (sj < NN) && ((start_mask >> si) & 1ULL) && ((start_mask >> sj) & 1ULL);
    if (active) {
      const int p = ((pair_mask >> si) & 1ULL) ? 2 : 1;
      const int q = ((pair_mask >> sj) & 1ULL) ? 2 : 1;
      double c00 = 0, c01 = 0, c10 = 0, c11 = 0;
      int k = si;
      while (k < sj) {
        const bool kp = (pair_mask >> k) & 1ULL;
        double f00 = FF(si, k);
        double f01 = kp ? (double)FF(si, k + 1) : 0.0;
        double f10 = (p == 2) ? (double)FF(si + 1, k) : 0.0;
        double f11 = (p == 2 && kp) ? (double)FF(si + 1, k + 1) : 0.0;
        double t00 = TF(k, sj);
        double t01 = (q == 2) ? TF(k, sj + 1) : 0.0;
        double t10 = kp ? TF(k + 1, sj) : 0.0;
        double t11 = (kp && q == 2) ? TF(k + 1, sj + 1) : 0.0;
        c00 += f00 * t00 + f01 * t10;
        c01 += f00 * t01 + f01 * t11;
        c10 += f10 * t00 + f11 * t10;
        c11 += f10 * t01 + f11 * t11;
        k += kp ? 2 : 1;
      }
      k = si + p;
      while (k <= sj) {
        const bool kp = (pair_mask >> k) & 1ULL;
        double t00 = TF(si, k);
        double t01 = kp ? TF(si, k + 1) : 0.0;
        double t10 = (p == 2) ? TF(si + 1, k) : 0.0;
        double t11 = (p == 2 && kp) ? TF(si + 1, k + 1) : 0.0;
        double f00 = FF(k, sj);
        double f01 = (q == 2) ? (double)FF(k, sj + 1) : 0.0;
        double f10 = kp ? (double)FF(k + 1, sj) : 0.0;
        double f11 = (kp && q == 2) ? (double)FF(k + 1, sj + 1) : 0.0;
        c00 -= t00 * f00 + t01 * f10;
        c01 -= t00 * f01 + t01 * f11;
        c10 -= t10 * f00 + t11 * f10;
        c11 -= t10 * f01 + t11 * f11;
        k += kp ? 2 : 1;
      }
      // solve T_ii X - X T_jj = C
      double x00 = 0, x01 = 0, x10 = 0, x11 = 0;
      if (p == 1 && q == 1) {
        x00 = c00 / guard_d(TF(si, si) - TF(sj, sj));
      } else if (p == 2 && q == 1) {
        double t = TF(sj, sj);
        double m00 = TF(si, si) - t, m01 = TF(si, si + 1);
        double m10 = TF(si + 1, si), m11 = TF(si + 1, si + 1) - t;
        double dd = guard_d(m00 * m11 - m01 * m10);
        x00 = (m11 * c00 - m01 * c10) / dd;
        x10 = (m00 * c10 - m10 * c00) / dd;
      } else if (p == 1 && q == 2) {
        double t = TF(si, si);
        double m00 = t - TF(sj, sj), m01 = -TF(sj, sj + 1);
        double m10 = -TF(sj + 1, sj), m11 = t - TF(sj + 1, sj + 1);
        double dd = guard_d(m00 * m11 - m01 * m10);
        x00 = (c00 * m11 - c01 * m10) / dd;
        x01 = (c01 * m00 - c00 * m01) / dd;
      } else {
        double A00 = TF(si, si), A01 = TF(si, si + 1);
        double A10 = TF(si + 1, si), A11 = TF(si + 1, si + 1);
        double B00 = TF(sj, sj), B01 = TF(sj, sj + 1);
        double B10 = TF(sj + 1, sj), B11 = TF(sj + 1, sj + 1);
        double M[4][5] = {
            {A00 - B00, A01, -B10, 0.0, c00},
            {A10, A11 - B00, 0.0, -B10, c10},
            {-B01, 0.0, A00 - B11, A01, c01},
            {0.0, -B01, A10, A11 - B11, c11}};
        #pragma unroll
        for (int cc = 0; cc < 4; ++cc) {
          #pragma unroll
          for (int rr2 = cc + 1; rr2 < 4; ++rr2) {  // bubble-max partial pivot
            bool sw = fabs(M[rr2][cc]) > fabs(M[cc][cc]);
            #pragma unroll
            for (int t2 = cc; t2 < 5; ++t2) {
              double aa = M[cc][t2], bb = M[rr2][t2];
              M[cc][t2] = sw ? bb : aa;
              M[rr2][t2] = sw ? aa : bb;
            }
          }
          double inv = 1.0 / guard_d(M[cc][cc]);
          #pragma unroll
          for (int rr2 = cc + 1; rr2 < 4; ++rr2) {
            double f2 = M[rr2][cc] * inv;
            #pragma unroll
            for (int t2 = cc; t2 < 5; ++t2) M[rr2][t2] -= f2 * M[cc][t2];
          }
        }
        double z3 = M[3][4] / guard_d(M[3][3]);
        double z2 = (M[2][4] - M[2][3] * z3) / guard_d(M[2][2]);
        double z1 = (M[1][4] - M[1][3] * z3 - M[1][2] * z2) / guard_d(M[1][1]);
        double z0 = (M[0][4] - M[0][3] * z3 - M[0][2] * z2 - M[0][1] * z1) / guard_d(M[0][0]);
        x00 = z0; x10 = z1; x01 = z2; x11 = z3;
      }
      FF(si, sj) = (float)x00;
      if (q == 2) FF(si, sj + 1) = (float)x01;
      if (p == 2) {
        FF(si + 1, sj) = (float)x10;
        if (q == 2) FF(si + 1, sj + 1) = (float)x11;
      }
    }
    __syncthreads();
  }

  // ---------------- symmetrize + eps shift ----------------
  {
    const int r = lane;
    for (int j = r + 1; j < NN; ++j) {
      float v = 0.5f * (FF(r, j) + FF(j, r));
      FF(r, j) = v;
      FF(j, r) = v;
    }
    FF(r, r) += (float)cshift;
  }
  __syncthreads();

  // ---------------- stage Q into dead float-T region; out = Q Fs Q^T ----------------
  float* Qs = Tf;  // T dead after Parlett
  for (int c = 0; c < NN; ++c) Qs[lane * LDP + c] = Qg[c * NN + lane];
  __syncthreads();

  float acc[NN];
  #pragma unroll
  for (int i = 0; i < NN; ++i) acc[i] = 0.0f;
  for (int k = 0; k < NN; ++k) {  // W = Q * Fs ; lane = column j
    float f = FF(k, lane);
    #pragma unroll
    for (int i = 0; i < NN; ++i) acc[i] += Qs[i * LDP + k] * f;
  }
  __syncthreads();  // all Fs reads done before W overwrites the region
  float* W = Fp;    // F dead after GEMM1
  #pragma unroll
  for (int i = 0; i < NN; ++i) W[i * LDP + lane] = acc[i];
  __syncthreads();

  #pragma unroll
  for (int i = 0; i < NN; ++i) acc[i] = 0.0f;
  for (int k = 0; k < NN; ++k) {  // out = W * Q^T ; lane = column j
    float qv = Qs[lane * LDP + k];
    #pragma unroll
    for (int i = 0; i < NN; ++i) acc[i] += W[i * LDP + k] * qv;
  }
  #pragma unroll
  for (int i = 0; i < NN; ++i) dst[i * NN + lane] = acc[i];
}

extern "C" void kernel_launch(void* const* d_in, const int* in_sizes, int n_in,
                              void* d_out, int out_size, void* d_ws, size_t ws_size,
                              hipStream_t stream) {
  const float* x = (const float*)d_in[0];
  float* out = (float*)d_out;
  const int nmat = in_sizes[0] / (NN * NN);  // 4096
  spd64_kernel<<<nmat, 64, 0, stream>>>(x, out);
}